// Round 1
// 523.479 us; speedup vs baseline: 2.5884x; 2.5884x over previous
//
#include <hip/hip_runtime.h>
#include <hip/hip_bf16.h>
#include <stdint.h>

typedef __attribute__((ext_vector_type(8))) __bf16 bf16x8;
typedef __attribute__((ext_vector_type(4))) float  f32x4;

// ---------- bf16 helpers (bf16 pairs packed in uint32, little-endian) ----------
__device__ __forceinline__ float bflo(uint32_t p){ return __uint_as_float(p << 16); }
__device__ __forceinline__ float bfhi(uint32_t p){ return __uint_as_float(p & 0xffff0000u); }
__device__ __forceinline__ uint16_t f2bf(float f){
    uint32_t u = __float_as_uint(f);
    uint32_t r = (u + 0x7fffu + ((u >> 16) & 1u)) >> 16;   // RNE
    return (uint16_t)r;
}
__device__ __forceinline__ uint32_t packbf(float a, float b){
    return (uint32_t)f2bf(a) | ((uint32_t)f2bf(b) << 16);
}
__device__ __forceinline__ f32x4 MFMA(bf16x8 a, bf16x8 b, f32x4 c){
    return __builtin_amdgcn_mfma_f32_16x16x32_bf16(a, b, c, 0, 0, 0);
}

// Mean buffer lives in the SECOND HALF of each f32 Emb row (u32 units):
//   Mb(row) = Emb u32 [row*128 + 64, row*128 + 128).
// Xbf (layer-1 bf16 input) lives in the FIRST HALF: Emb u32 [row*128, row*128+64).
#define MB_IDX(row, lane) ((size_t)(row) * 128 + 64 + (lane))

// ---------- CSR build ----------
__global__ void k_deg(const int* __restrict__ dst, int* __restrict__ counts, int E){
    int e = blockIdx.x * 256 + threadIdx.x;
    if (e < E) atomicAdd(&counts[dst[e]], 1);
}

__global__ void k_scan1(const int* __restrict__ counts, int* __restrict__ bsums, int N){
    __shared__ int lds[256];
    int t = threadIdx.x;
    int base = blockIdx.x * 2048 + t * 8;
    int s = 0;
    #pragma unroll
    for (int i = 0; i < 8; ++i){ int idx = base + i; s += (idx < N) ? counts[idx] : 0; }
    lds[t] = s; __syncthreads();
    for (int off = 128; off > 0; off >>= 1){
        if (t < off) lds[t] += lds[t + off];
        __syncthreads();
    }
    if (t == 0) bsums[blockIdx.x] = lds[0];
}

__global__ void k_scan2(int* bsums, int NB){
    int run = 0;
    for (int i = 0; i < NB; ++i){ int v = bsums[i]; bsums[i] = run; run += v; }
}

__global__ void k_scan3(const int* __restrict__ counts, const int* __restrict__ bsums,
                        int* __restrict__ offs, int N){
    __shared__ int lds[256];
    int t = threadIdx.x;
    int base = blockIdx.x * 2048 + t * 8;
    int local[8];
    int s = 0;
    #pragma unroll
    for (int i = 0; i < 8; ++i){
        int idx = base + i;
        int v = (idx < N) ? counts[idx] : 0;
        local[i] = v; s += v;
    }
    lds[t] = s; __syncthreads();
    for (int off = 1; off < 256; off <<= 1){
        int v = (t >= off) ? lds[t - off] : 0;
        __syncthreads();
        lds[t] += v;
        __syncthreads();
    }
    int run = bsums[blockIdx.x] + (lds[t] - s);
    #pragma unroll
    for (int i = 0; i < 8; ++i){
        int idx = base + i;
        if (idx < N){ offs[idx] = run; run += local[i]; }
    }
}

__global__ void k_fill(const int* __restrict__ src, const int* __restrict__ dst,
                       const int* __restrict__ offs, int* __restrict__ cursor,
                       int* __restrict__ ssrc, int E){
    int e = blockIdx.x * 256 + threadIdx.x;
    if (e < E){
        int d = dst[e];
        int p = atomicAdd(&cursor[d], 1);
        ssrc[offs[d] + p] = src[e];
    }
}

// ---------- x -> bf16 hi (into Emb first half) + bf16 lo residual ----------
__global__ __launch_bounds__(256) void k_x2bf(const float* __restrict__ X,
        uint32_t* __restrict__ XbfE, uint32_t* __restrict__ Xlo, int N){
    int i = blockIdx.x * 256 + threadIdx.x;          // pair index, total N*64
    if (i >= N * 64) return;
    int row = i >> 6, lane = i & 63;
    float2 v = *(const float2*)(X + (size_t)i * 2);
    uint16_t h0 = f2bf(v.x), h1 = f2bf(v.y);
    float r0 = v.x - __uint_as_float((uint32_t)h0 << 16);
    float r1 = v.y - __uint_as_float((uint32_t)h1 << 16);
    XbfE[(size_t)row * 128 + lane] = (uint32_t)h0 | ((uint32_t)h1 << 16);
    Xlo[(size_t)i] = packbf(r0, r1);
}

// ---------- weight prep: Wt[c][k] bf16 hi/lo, k<128 -> Wl, k>=128 -> scale*Wr ----------
__global__ void k_wprep(const float* __restrict__ Wl, const float* __restrict__ Wr,
                        const float* __restrict__ scale,
                        uint16_t* __restrict__ Whi, uint16_t* __restrict__ Wlo){
    int idx = blockIdx.x * 256 + threadIdx.x;        // [0, 32768) = c*256 + k
    int c = idx >> 8, k = idx & 255;
    float v;
    if (k < 128){
        v = Wl[k * 128 + c];
    } else {
        v = Wr[(k - 128) * 128 + c];
        if (scale) v *= scale[k - 128];
    }
    uint16_t h = f2bf(v);
    float r = v - __uint_as_float((uint32_t)h << 16);
    Whi[idx] = h;
    Wlo[idx] = f2bf(r);
}

// ---------- neighbor mean: one wave per node; bf16 source rows ----------
// MODE 0: raw mean.  MODE 1: mean + BN fold (shift only when cnt>0, matching ref).
template<int MODE>
__global__ __launch_bounds__(256) void k_agg(
        const uint32_t* __restrict__ Src, int sstr,
        const int* __restrict__ offs, const int* __restrict__ counts,
        const int* __restrict__ ssrc,
        const float* __restrict__ bnscale, const float* __restrict__ bnshift,
        uint32_t* __restrict__ MbBase, int N){
    int lane = threadIdx.x & 63;
    int node = blockIdx.x * 4 + (threadIdx.x >> 6);
    if (node >= N) return;
    int cnt = counts[node];
    if (cnt < 0) cnt = 0;
    int off = offs[node];
    float a0 = 0.f, a1 = 0.f;
    for (int j = 0; j < cnt; ++j){
        int s = ssrc[off + j];
        s = (s < 0) ? 0 : ((s >= N) ? (N - 1) : s);
        uint32_t p = Src[(size_t)s * sstr + lane];
        a0 += bflo(p); a1 += bfhi(p);
    }
    float inv = 1.0f / fmaxf((float)cnt, 1.0f);
    a0 *= inv; a1 *= inv;
    if (MODE == 1){
        int c0 = lane * 2;
        float sh0 = (cnt > 0) ? bnshift[c0]     : 0.f;   // ref: zero-degree mean == 0
        float sh1 = (cnt > 0) ? bnshift[c0 + 1] : 0.f;
        a0 = a0 * bnscale[c0]     + sh0;
        a1 = a1 * bnscale[c0 + 1] + sh1;
    }
    MbBase[MB_IDX(node, lane)] = packbf(a0, a1);
}

// ---------- MFMA dual-GEMM (K=256 = [mean|own]) + L2-normalize ----------
// Wave owns 32 rows (2 m-tiles), all 128 cols (8 n-tiles).
// A frag:  lane holds row (lane&15), k = 32*kt + 8*(lane>>4) + e  (contiguous 16B)
// B frag:  lane holds col (lane&15) of Wt[col][k], same contiguous-k slice
// C/D:     col = lane&15, row = 4*(lane>>4) + reg   (m89-verified)
// MODE 0: own=Xbf (+Xlo correction); out=relu(norm(.)); Hbf store + BN sums.
// MODE 1: own=Hbf (BN folded into Whi/Wlo/bias); out=norm(.); Emb f32 + preds.
template<int MODE>
__global__ __launch_bounds__(256) void k_gemm(
        const uint32_t* Own,                 // MODE0: Xbf in Emb rows (stride 128); MODE1: Hbf (stride 64)
        const uint32_t* OwnLo,               // MODE0 only: Xlo (stride 64; aliases HbfOut)
        const uint32_t* Mb,                  // bf16 means at Emb rows' 2nd half
        const uint16_t* __restrict__ Whi, const uint16_t* __restrict__ Wlo, // [128][256]
        const float* __restrict__ bias,      // [128] effective bias
        uint32_t* HbfOut,                    // MODE0 out (aliases OwnLo; alias-safe per-wave)
        float* Emb,                          // MODE1 out (aliases Mb rows; reads precede writes)
        float* __restrict__ bnsum, float* __restrict__ bnsumsq,             // MODE0
        const float* __restrict__ fcW, const float* __restrict__ fcb,       // MODE1
        float* __restrict__ preds, int N){
    __shared__ float lsum[128], lsq[128];
    const int lane = threadIdx.x & 63;
    const int wid  = threadIdx.x >> 6;
    const int l15  = lane & 15;
    const int g    = lane >> 4;
    const int ostr = (MODE == 0) ? 128 : 64;
    const int rowb = blockIdx.x * 128 + wid * 32;

    if (MODE == 0){
        if (threadIdx.x < 128){ lsum[threadIdx.x] = 0.f; lsq[threadIdx.x] = 0.f; }
        __syncthreads();
    }

    int ar0 = rowb + l15;      if (ar0 >= N) ar0 = N - 1;   // clamped dup rows: discarded
    int ar1 = rowb + 16 + l15; if (ar1 >= N) ar1 = N - 1;

    const uint32_t* mp0 = Mb  + (size_t)ar0 * 128 + 64 + g * 4;
    const uint32_t* mp1 = Mb  + (size_t)ar1 * 128 + 64 + g * 4;
    const uint32_t* op0 = Own + (size_t)ar0 * ostr + g * 4;
    const uint32_t* op1 = Own + (size_t)ar1 * ostr + g * 4;

    f32x4 acc0[8], acc1[8];
    const f32x4 zero = {0.f, 0.f, 0.f, 0.f};
    #pragma unroll
    for (int t = 0; t < 8; ++t){ acc0[t] = zero; acc1[t] = zero; }

    const uint16_t* wb = Whi + (size_t)l15 * 256 + g * 8;
    const uint16_t* wl = Wlo + (size_t)l15 * 256 + g * 8;

    #pragma unroll
    for (int kt = 0; kt < 8; ++kt){
        bf16x8 a0, a1;
        if (kt < 4){
            a0 = *(const bf16x8*)(mp0 + kt * 16);
            a1 = *(const bf16x8*)(mp1 + kt * 16);
        } else {
            a0 = *(const bf16x8*)(op0 + (kt - 4) * 16);
            a1 = *(const bf16x8*)(op1 + (kt - 4) * 16);
        }
        #pragma unroll
        for (int t = 0; t < 8; ++t){
            const size_t co = (size_t)t * 4096 + kt * 32;
            bf16x8 bh = *(const bf16x8*)(wb + co);
            bf16x8 bl = *(const bf16x8*)(wl + co);
            acc0[t] = MFMA(a0, bh, acc0[t]);
            acc1[t] = MFMA(a1, bh, acc1[t]);
            acc0[t] = MFMA(a0, bl, acc0[t]);
            acc1[t] = MFMA(a1, bl, acc1[t]);
        }
        if (MODE == 0 && kt >= 4){                      // x_lo correction (own half only)
            bf16x8 c0 = *(const bf16x8*)(OwnLo + (size_t)ar0 * 64 + g * 4 + (kt - 4) * 16);
            bf16x8 c1 = *(const bf16x8*)(OwnLo + (size_t)ar1 * 64 + g * 4 + (kt - 4) * 16);
            #pragma unroll
            for (int t = 0; t < 8; ++t){
                const size_t co = (size_t)t * 4096 + kt * 32;
                bf16x8 bh = *(const bf16x8*)(wb + co);
                acc0[t] = MFMA(c0, bh, acc0[t]);
                acc1[t] = MFMA(c1, bh, acc1[t]);
            }
        }
    }

    // ---- epilogue ----
    float bv[8];
    #pragma unroll
    for (int t = 0; t < 8; ++t) bv[t] = bias[t * 16 + l15];

    float fw[4]; float fb = 0.f;
    if (MODE == 1){
        #pragma unroll
        for (int t = 0; t < 4; ++t) fw[t] = fcW[t * 16 + l15];
        fb = fcb[0];
    }

    float pbs[8], pbq[8];
    #pragma unroll
    for (int t = 0; t < 8; ++t){ pbs[t] = 0.f; pbq[t] = 0.f; }

    #pragma unroll
    for (int m = 0; m < 2; ++m){
        #pragma unroll
        for (int j = 0; j < 4; ++j){
            int orow = rowb + m * 16 + 4 * g + j;
            bool valid = orow < N;
            float o[8]; float ss = 0.f;
            #pragma unroll
            for (int t = 0; t < 8; ++t){
                o[t] = (m == 0 ? acc0[t][j] : acc1[t][j]) + bv[t];
                ss += o[t] * o[t];
            }
            ss += __shfl_xor(ss, 1, 64);
            ss += __shfl_xor(ss, 2, 64);
            ss += __shfl_xor(ss, 4, 64);
            ss += __shfl_xor(ss, 8, 64);
            float inv = 1.0f / fmaxf(sqrtf(ss), 1e-12f);
            if (MODE == 0){
                #pragma unroll
                for (int t = 0; t < 8; ++t){
                    float v = fmaxf(o[t] * inv, 0.f);
                    float pv = __shfl_xor(v, 1, 64);          // partner col (uniform exec)
                    if (valid){
                        pbs[t] += v; pbq[t] += v * v;
                        if (!(lane & 1))
                            HbfOut[(size_t)orow * 64 + t * 8 + (l15 >> 1)] = packbf(v, pv);
                    }
                }
            } else {
                float p = 0.f;
                #pragma unroll
                for (int t = 0; t < 8; ++t){
                    float v = o[t] * inv;
                    if (valid) Emb[(size_t)orow * 128 + t * 16 + l15] = v;
                    if (t < 4) p += v * fw[t];
                }
                p += __shfl_xor(p, 1, 64);
                p += __shfl_xor(p, 2, 64);
                p += __shfl_xor(p, 4, 64);
                p += __shfl_xor(p, 8, 64);
                if (valid && l15 == 0) preds[orow] = p + fb;
            }
        }
    }

    if (MODE == 0){
        #pragma unroll
        for (int t = 0; t < 8; ++t){
            pbs[t] += __shfl_xor(pbs[t], 16, 64);
            pbs[t] += __shfl_xor(pbs[t], 32, 64);
            pbq[t] += __shfl_xor(pbq[t], 16, 64);
            pbq[t] += __shfl_xor(pbq[t], 32, 64);
        }
        if (lane < 16){
            #pragma unroll
            for (int t = 0; t < 8; ++t){
                atomicAdd(&lsum[t * 16 + lane], pbs[t]);
                atomicAdd(&lsq [t * 16 + lane], pbq[t]);
            }
        }
        __syncthreads();
        if (threadIdx.x < 128){
            atomicAdd(&bnsum[threadIdx.x],   lsum[threadIdx.x]);
            atomicAdd(&bnsumsq[threadIdx.x], lsq[threadIdx.x]);
        }
    }
}

// ---------- BN finalize + effective layer-2 bias (b2 + shift @ W2r) ----------
__global__ void k_bnfinal(const float* __restrict__ bnsum, const float* __restrict__ bnsumsq,
                          const float* __restrict__ gamma, const float* __restrict__ beta,
                          const float* __restrict__ W2r, const float* __restrict__ b2,
                          float* __restrict__ scale, float* __restrict__ shift,
                          float* __restrict__ bias2, int N){
    __shared__ float sh_l[128];
    int t = threadIdx.x;
    float invN = 1.0f / (float)N;
    float mu  = bnsum[t] * invN;
    float var = fmaxf(bnsumsq[t] * invN - mu * mu, 0.f);
    float istd = 1.0f / sqrtf(var + 1e-5f);
    float sc = gamma[t] * istd;
    float sf = beta[t] - mu * sc;
    scale[t] = sc; shift[t] = sf; sh_l[t] = sf;
    __syncthreads();
    float acc = b2[t];
    for (int k = 0; k < 128; ++k) acc += sh_l[k] * W2r[k * 128 + t];
    bias2[t] = acc;
}

__global__ void k_sent(float* __restrict__ preds, int N, float val){
    int i = blockIdx.x * 256 + threadIdx.x;
    if (i < N) preds[i] = val;
}

// ---------- launch ----------
extern "C" void kernel_launch(void* const* d_in, const int* in_sizes, int n_in,
                              void* d_out, int out_size, void* d_ws, size_t ws_size,
                              hipStream_t stream){
    const int N = in_sizes[0] / 128;
    const int E = in_sizes[1] / 2;

    const float* x    = (const float*)d_in[0];
    const int*   ei   = (const int*)d_in[1];
    const int*   src  = ei;
    const int*   dst  = ei + E;
    const float* W1l  = (const float*)d_in[2];
    const float* b1   = (const float*)d_in[3];
    const float* W1r  = (const float*)d_in[4];
    const float* gam  = (const float*)d_in[5];
    const float* bet  = (const float*)d_in[6];
    const float* W2l  = (const float*)d_in[7];
    const float* b2   = (const float*)d_in[8];
    const float* W2r  = (const float*)d_in[9];
    const float* fcW  = (const float*)d_in[10];
    const float* fcb  = (const float*)d_in[11];

    float* preds = (float*)d_out;                 // f32 [N]
    float* Emb   = preds + N;                     // f32 [N,128]
    uint32_t* EmbU = (uint32_t*)Emb;              // Xbf (1st half) + Mb (2nd half) scratch

    char* w = (char*)d_ws;
    auto carve = [&](size_t bytes){ char* p = w; w += (bytes + 255) & ~(size_t)255; return p; };
    int*   counts  = (int*)  carve((size_t)N * 4);
    int*   offs    = (int*)  carve((size_t)N * 4);
    int*   cursor  = (int*)  carve((size_t)N * 4);
    int*   bsums   = (int*)  carve(256 * 4);
    float* bnsum   = (float*)carve(128 * 4);      // contiguous with bnsumsq (one memset)
    float* bnsumsq = (float*)carve(128 * 4);
    float* bnscale = (float*)carve(128 * 4);
    float* bnshift = (float*)carve(128 * 4);
    float* bias2   = (float*)carve(128 * 4);
    int*   ssrc    = (int*)  carve((size_t)E * 4);
    uint32_t* HbfXlo = (uint32_t*)carve((size_t)N * 256);  // Xlo then Hbf (overlay, alias-safe)
    uint16_t* Whi1 = (uint16_t*)carve(65536);
    uint16_t* Wlo1 = (uint16_t*)carve(65536);
    uint16_t* Whi2 = (uint16_t*)carve(65536);
    uint16_t* Wlo2 = (uint16_t*)carve(65536);
    size_t need = (size_t)(w - (char*)d_ws);
    if (ws_size < need){
        float val = 1024.f + 4.f * (float)((ws_size >> 20) > 255 ? 255 : (ws_size >> 20));
        k_sent<<<(N + 255) / 256, 256, 0, stream>>>(preds, N, val);
        return;
    }

    hipMemsetAsync(counts, 0, (size_t)N * 4, stream);
    hipMemsetAsync(cursor, 0, (size_t)N * 4, stream);
    hipMemsetAsync(bnsum,  0, 1024, stream);

    const int eb = (E + 255) / 256;
    const int NB = (N + 2047) / 2048;
    const int ab = (N + 3) / 4;
    const int gb = (N + 127) / 128;
    const int xb = (N * 64 + 255) / 256;

    k_deg  <<<eb, 256, 0, stream>>>(dst, counts, E);
    k_scan1<<<NB, 256, 0, stream>>>(counts, bsums, N);
    k_scan2<<<1,    1, 0, stream>>>(bsums, NB);
    k_scan3<<<NB, 256, 0, stream>>>(counts, bsums, offs, N);
    k_fill <<<eb, 256, 0, stream>>>(src, dst, offs, cursor, ssrc, E);

    k_x2bf <<<xb, 256, 0, stream>>>(x, EmbU, HbfXlo, N);
    k_wprep<<<128, 256, 0, stream>>>(W1l, W1r, nullptr, Whi1, Wlo1);

    // layer 1
    k_agg<0> <<<ab, 256, 0, stream>>>(EmbU, 128, offs, counts, ssrc,
                                      nullptr, nullptr, EmbU, N);
    k_gemm<0><<<gb, 256, 0, stream>>>(EmbU, HbfXlo, EmbU, Whi1, Wlo1, b1,
                                      HbfXlo, nullptr, bnsum, bnsumsq,
                                      nullptr, nullptr, nullptr, N);
    k_bnfinal<<<1, 128, 0, stream>>>(bnsum, bnsumsq, gam, bet, W2r, b2,
                                     bnscale, bnshift, bias2, N);
    k_wprep<<<128, 256, 0, stream>>>(W2l, W2r, bnscale, Whi2, Wlo2);

    // layer 2
    k_agg<1> <<<ab, 256, 0, stream>>>(HbfXlo, 64, offs, counts, ssrc,
                                      bnscale, bnshift, EmbU, N);
    k_gemm<1><<<gb, 256, 0, stream>>>(HbfXlo, nullptr, EmbU, Whi2, Wlo2, bias2,
                                      nullptr, Emb, nullptr, nullptr,
                                      fcW, fcb, preds, N);
}

// Round 2
// 380.831 us; speedup vs baseline: 3.5580x; 1.3746x over previous
//
#include <hip/hip_runtime.h>
#include <hip/hip_bf16.h>
#include <stdint.h>

typedef __attribute__((ext_vector_type(8))) __bf16 bf16x8;
typedef __attribute__((ext_vector_type(4))) float  f32x4;

// ---------- bf16 helpers (bf16 pairs packed in uint32, little-endian) ----------
__device__ __forceinline__ float bflo(uint32_t p){ return __uint_as_float(p << 16); }
__device__ __forceinline__ float bfhi(uint32_t p){ return __uint_as_float(p & 0xffff0000u); }
__device__ __forceinline__ uint16_t f2bf(float f){
    uint32_t u = __float_as_uint(f);
    uint32_t r = (u + 0x7fffu + ((u >> 16) & 1u)) >> 16;   // RNE
    return (uint16_t)r;
}
__device__ __forceinline__ uint32_t packbf(float a, float b){
    return (uint32_t)f2bf(a) | ((uint32_t)f2bf(b) << 16);
}
__device__ __forceinline__ f32x4 MFMA(bf16x8 a, bf16x8 b, f32x4 c){
    return __builtin_amdgcn_mfma_f32_16x16x32_bf16(a, b, c, 0, 0, 0);
}

// Mean buffer lives in the SECOND HALF of each f32 Emb row (u32 units):
//   Mb(row) = Emb u32 [row*128 + 64, row*128 + 128).
// Xbf (layer-1 bf16 input) lives in the FIRST HALF: Emb u32 [row*128, row*128+64).
#define MB_IDX(row, lane) ((size_t)(row) * 128 + 64 + (lane))

// ---------- CSR build ----------
__global__ void k_deg(const int* __restrict__ dst, int* __restrict__ counts, int E){
    int e = blockIdx.x * 256 + threadIdx.x;
    if (e < E) atomicAdd(&counts[dst[e]], 1);
}

__global__ void k_scan1(const int* __restrict__ counts, int* __restrict__ bsums, int N){
    __shared__ int lds[256];
    int t = threadIdx.x;
    int base = blockIdx.x * 2048 + t * 8;
    int s = 0;
    #pragma unroll
    for (int i = 0; i < 8; ++i){ int idx = base + i; s += (idx < N) ? counts[idx] : 0; }
    lds[t] = s; __syncthreads();
    for (int off = 128; off > 0; off >>= 1){
        if (t < off) lds[t] += lds[t + off];
        __syncthreads();
    }
    if (t == 0) bsums[blockIdx.x] = lds[0];
}

__global__ void k_scan2(int* bsums, int NB){
    int run = 0;
    for (int i = 0; i < NB; ++i){ int v = bsums[i]; bsums[i] = run; run += v; }
}

__global__ void k_scan3(const int* __restrict__ counts, const int* __restrict__ bsums,
                        int* __restrict__ offs, int N){
    __shared__ int lds[256];
    int t = threadIdx.x;
    int base = blockIdx.x * 2048 + t * 8;
    int local[8];
    int s = 0;
    #pragma unroll
    for (int i = 0; i < 8; ++i){
        int idx = base + i;
        int v = (idx < N) ? counts[idx] : 0;
        local[i] = v; s += v;
    }
    lds[t] = s; __syncthreads();
    for (int off = 1; off < 256; off <<= 1){
        int v = (t >= off) ? lds[t - off] : 0;
        __syncthreads();
        lds[t] += v;
        __syncthreads();
    }
    int run = bsums[blockIdx.x] + (lds[t] - s);
    #pragma unroll
    for (int i = 0; i < 8; ++i){
        int idx = base + i;
        if (idx < N){ offs[idx] = run; run += local[i]; }
    }
}

__global__ void k_fill(const int* __restrict__ src, const int* __restrict__ dst,
                       const int* __restrict__ offs, int* __restrict__ cursor,
                       int* __restrict__ ssrc, int E){
    int e = blockIdx.x * 256 + threadIdx.x;
    if (e < E){
        int d = dst[e];
        int p = atomicAdd(&cursor[d], 1);
        ssrc[offs[d] + p] = src[e];
    }
}

// ---------- x -> bf16 hi (into Emb first half) + bf16 lo residual ----------
__global__ __launch_bounds__(256) void k_x2bf(const float* __restrict__ X,
        uint32_t* __restrict__ XbfE, uint32_t* __restrict__ Xlo, int N){
    int i = blockIdx.x * 256 + threadIdx.x;          // pair index, total N*64
    if (i >= N * 64) return;
    int row = i >> 6, lane = i & 63;
    float2 v = *(const float2*)(X + (size_t)i * 2);
    uint16_t h0 = f2bf(v.x), h1 = f2bf(v.y);
    float r0 = v.x - __uint_as_float((uint32_t)h0 << 16);
    float r1 = v.y - __uint_as_float((uint32_t)h1 << 16);
    XbfE[(size_t)row * 128 + lane] = (uint32_t)h0 | ((uint32_t)h1 << 16);
    Xlo[(size_t)i] = packbf(r0, r1);
}

// ---------- weight prep: packed K-sliced layout for LDS staging ----------
// Wpk u16 layout: [kt(8)][sel(2: hi,lo)][c(128)][kk(32)]  (slice = 16 KiB)
// source: k<128 -> Wl[k][c], k>=128 -> scale*Wr[k-128][c]
__global__ void k_wprep(const float* __restrict__ Wl, const float* __restrict__ Wr,
                        const float* __restrict__ scale,
                        uint16_t* __restrict__ Wpk){
    int idx = blockIdx.x * 256 + threadIdx.x;        // [0, 32768) = c*256 + k
    int c = idx >> 8, k = idx & 255;
    float v;
    if (k < 128){
        v = Wl[k * 128 + c];
    } else {
        v = Wr[(k - 128) * 128 + c];
        if (scale) v *= scale[k - 128];
    }
    uint16_t h = f2bf(v);
    float r = v - __uint_as_float((uint32_t)h << 16);
    int kt = k >> 5, kk = k & 31;
    size_t base = (size_t)kt * 8192 + (size_t)c * 32 + kk;
    Wpk[base]        = h;
    Wpk[base + 4096] = f2bf(r);
}

// ---------- neighbor mean: one wave per node; bf16 source rows ----------
// MODE 0: raw mean.  MODE 1: mean + BN fold (shift only when cnt>0, matching ref).
template<int MODE>
__global__ __launch_bounds__(256) void k_agg(
        const uint32_t* __restrict__ Src, int sstr,
        const int* __restrict__ offs, const int* __restrict__ counts,
        const int* __restrict__ ssrc,
        const float* __restrict__ bnscale, const float* __restrict__ bnshift,
        uint32_t* __restrict__ MbBase, int N){
    int lane = threadIdx.x & 63;
    int node = blockIdx.x * 4 + (threadIdx.x >> 6);
    if (node >= N) return;
    int cnt = counts[node];
    if (cnt < 0) cnt = 0;
    int off = offs[node];
    float a0 = 0.f, a1 = 0.f;
    int j = 0;
    for (; j + 4 <= cnt; j += 4){                     // 4 independent gathers in flight
        int s0 = ssrc[off + j];
        int s1 = ssrc[off + j + 1];
        int s2 = ssrc[off + j + 2];
        int s3 = ssrc[off + j + 3];
        s0 = (s0 < 0) ? 0 : ((s0 >= N) ? (N - 1) : s0);
        s1 = (s1 < 0) ? 0 : ((s1 >= N) ? (N - 1) : s1);
        s2 = (s2 < 0) ? 0 : ((s2 >= N) ? (N - 1) : s2);
        s3 = (s3 < 0) ? 0 : ((s3 >= N) ? (N - 1) : s3);
        uint32_t p0 = Src[(size_t)s0 * sstr + lane];
        uint32_t p1 = Src[(size_t)s1 * sstr + lane];
        uint32_t p2 = Src[(size_t)s2 * sstr + lane];
        uint32_t p3 = Src[(size_t)s3 * sstr + lane];
        a0 += bflo(p0) + bflo(p1) + bflo(p2) + bflo(p3);
        a1 += bfhi(p0) + bfhi(p1) + bfhi(p2) + bfhi(p3);
    }
    for (; j < cnt; ++j){
        int s = ssrc[off + j];
        s = (s < 0) ? 0 : ((s >= N) ? (N - 1) : s);
        uint32_t p = Src[(size_t)s * sstr + lane];
        a0 += bflo(p); a1 += bfhi(p);
    }
    float inv = 1.0f / fmaxf((float)cnt, 1.0f);
    a0 *= inv; a1 *= inv;
    if (MODE == 1){
        int c0 = lane * 2;
        float sh0 = (cnt > 0) ? bnshift[c0]     : 0.f;   // ref: zero-degree mean == 0
        float sh1 = (cnt > 0) ? bnshift[c0 + 1] : 0.f;
        a0 = a0 * bnscale[c0]     + sh0;
        a1 = a1 * bnscale[c0 + 1] + sh1;
    }
    MbBase[MB_IDX(node, lane)] = packbf(a0, a1);
}

// ---------- MFMA dual-GEMM (K=256 = [mean|own]) + L2-normalize ----------
// Wave owns 32 rows (2 m-tiles), all 128 cols (8 n-tiles).
// B staged per-kt in LDS (double-buffered, global_load_lds w16), shared by 4 waves.
// A frag:  lane holds row (lane&15), k = 32*kt + 8*(lane>>4) + e  (contiguous 16B)
// B frag:  lane holds col (lane&15) of Wt[col][k]  (ds_read_b128, conflict-free)
// C/D:     col = lane&15, row = 4*(lane>>4) + reg   (m89-verified)
// MODE 0: own=Xbf (+Xlo correction); out=relu(norm(.)); Hbf store + BN sums.
// MODE 1: own=Hbf (BN folded into Wpk/bias); out=norm(.); Emb f32 + preds.
template<int MODE>
__global__ __launch_bounds__(256) void k_gemm(
        const uint32_t* Own,                 // MODE0: Xbf in Emb rows (stride 128); MODE1: Hbf (stride 64)
        const uint32_t* OwnLo,               // MODE0 only: Xlo (stride 64; aliases HbfOut)
        const uint32_t* Mb,                  // bf16 means at Emb rows' 2nd half
        const uint32_t* __restrict__ Wpk,    // packed [kt][hi/lo][128][32] u16
        const float* __restrict__ bias,      // [128] effective bias
        uint32_t* HbfOut,                    // MODE0 out (aliases OwnLo; alias-safe per-wave)
        float* Emb,                          // MODE1 out (aliases Mb rows; reads precede writes)
        float* __restrict__ bnsum, float* __restrict__ bnsumsq,             // MODE0
        const float* __restrict__ fcW, const float* __restrict__ fcb,       // MODE1
        float* __restrict__ preds, int N){
    __shared__ uint32_t __align__(16) sB[2][4096];   // 2 x 16 KiB kt-slices of B
    __shared__ float lsum[128], lsq[128];
    const int lane = threadIdx.x & 63;
    const int wid  = threadIdx.x >> 6;
    const int l15  = lane & 15;
    const int g    = lane >> 4;
    const int ostr = (MODE == 0) ? 128 : 64;
    const int rowb = blockIdx.x * 128 + wid * 32;    // may be >= N: wave stays for staging

    // stage one kt-slice (16 KiB): each wave copies 4 KiB as 4 x 1 KiB chunks.
    // LDS dest is wave-uniform base (+ lane*16 by HW); global src is per-lane.
#define STAGE_KT(ktv, bufv) do {                                              \
        const uint32_t* gs_ = Wpk + (size_t)(ktv) * 4096 + wid * 1024 + lane * 4; \
        uint32_t* ls_ = &sB[bufv][wid * 1024];                                \
        __builtin_amdgcn_global_load_lds(gs_,       ls_,       16, 0, 0);     \
        __builtin_amdgcn_global_load_lds(gs_ + 256, ls_ + 256, 16, 0, 0);     \
        __builtin_amdgcn_global_load_lds(gs_ + 512, ls_ + 512, 16, 0, 0);     \
        __builtin_amdgcn_global_load_lds(gs_ + 768, ls_ + 768, 16, 0, 0);     \
    } while (0)

    STAGE_KT(0, 0);
    if (MODE == 0){
        if (threadIdx.x < 128){ lsum[threadIdx.x] = 0.f; lsq[threadIdx.x] = 0.f; }
    }
    __syncthreads();                                 // staged kt=0 visible

    int ar0 = rowb + l15;      if (ar0 >= N) ar0 = N - 1;   // clamped dup rows: discarded
    int ar1 = rowb + 16 + l15; if (ar1 >= N) ar1 = N - 1;

    const uint32_t* mp0 = Mb  + (size_t)ar0 * 128 + 64 + g * 4;
    const uint32_t* mp1 = Mb  + (size_t)ar1 * 128 + 64 + g * 4;
    const uint32_t* op0 = Own + (size_t)ar0 * ostr + g * 4;
    const uint32_t* op1 = Own + (size_t)ar1 * ostr + g * 4;

    f32x4 acc0[8], acc1[8];
    const f32x4 zero = {0.f, 0.f, 0.f, 0.f};
    #pragma unroll
    for (int t = 0; t < 8; ++t){ acc0[t] = zero; acc1[t] = zero; }

    #pragma unroll
    for (int kt = 0; kt < 8; ++kt){
        const int cur = kt & 1;
        if (kt < 7) STAGE_KT(kt + 1, cur ^ 1);       // prefetch next slice

        bf16x8 a0, a1, x0, x1;
        if (kt < 4){
            a0 = *(const bf16x8*)(mp0 + kt * 16);
            a1 = *(const bf16x8*)(mp1 + kt * 16);
        } else {
            a0 = *(const bf16x8*)(op0 + (kt - 4) * 16);
            a1 = *(const bf16x8*)(op1 + (kt - 4) * 16);
            if (MODE == 0){
                x0 = *(const bf16x8*)(OwnLo + (size_t)ar0 * 64 + g * 4 + (kt - 4) * 16);
                x1 = *(const bf16x8*)(OwnLo + (size_t)ar1 * 64 + g * 4 + (kt - 4) * 16);
            }
        }

        const uint32_t* sbase = &sB[cur][0];
        #pragma unroll
        for (int t = 0; t < 8; ++t){
            const uint32_t* bp = sbase + (t * 16 + l15) * 16 + g * 4;
            bf16x8 bh = *(const bf16x8*)bp;
            bf16x8 bl = *(const bf16x8*)(bp + 2048);
            acc0[t] = MFMA(a0, bh, acc0[t]);
            acc1[t] = MFMA(a1, bh, acc1[t]);
            if (MODE == 0 && kt >= 4){               // x_lo correction reuses bh
                acc0[t] = MFMA(x0, bh, acc0[t]);
                acc1[t] = MFMA(x1, bh, acc1[t]);
            }
            acc0[t] = MFMA(a0, bl, acc0[t]);
            acc1[t] = MFMA(a1, bl, acc1[t]);
        }
        __syncthreads();                             // slice kt+1 staged; buf[cur] free
    }
#undef STAGE_KT

    // ---- epilogue ----
    float bv[8];
    #pragma unroll
    for (int t = 0; t < 8; ++t) bv[t] = bias[t * 16 + l15];

    float fw[4]; float fb = 0.f;
    if (MODE == 1){
        #pragma unroll
        for (int t = 0; t < 4; ++t) fw[t] = fcW[t * 16 + l15];
        fb = fcb[0];
    }

    float pbs[8], pbq[8];
    #pragma unroll
    for (int t = 0; t < 8; ++t){ pbs[t] = 0.f; pbq[t] = 0.f; }

    #pragma unroll
    for (int m = 0; m < 2; ++m){
        #pragma unroll
        for (int j = 0; j < 4; ++j){
            int orow = rowb + m * 16 + 4 * g + j;
            bool valid = orow < N;
            float o[8]; float ss = 0.f;
            #pragma unroll
            for (int t = 0; t < 8; ++t){
                o[t] = (m == 0 ? acc0[t][j] : acc1[t][j]) + bv[t];
                ss += o[t] * o[t];
            }
            ss += __shfl_xor(ss, 1, 64);
            ss += __shfl_xor(ss, 2, 64);
            ss += __shfl_xor(ss, 4, 64);
            ss += __shfl_xor(ss, 8, 64);
            float inv = 1.0f / fmaxf(sqrtf(ss), 1e-12f);
            if (MODE == 0){
                #pragma unroll
                for (int t = 0; t < 8; ++t){
                    float v = fmaxf(o[t] * inv, 0.f);
                    float pv = __shfl_xor(v, 1, 64);          // partner col (uniform exec)
                    if (valid){
                        pbs[t] += v; pbq[t] += v * v;
                        if (!(lane & 1))
                            HbfOut[(size_t)orow * 64 + t * 8 + (l15 >> 1)] = packbf(v, pv);
                    }
                }
            } else {
                float p = 0.f;
                #pragma unroll
                for (int t = 0; t < 8; ++t){
                    float v = o[t] * inv;
                    if (valid) Emb[(size_t)orow * 128 + t * 16 + l15] = v;
                    if (t < 4) p += v * fw[t];
                }
                p += __shfl_xor(p, 1, 64);
                p += __shfl_xor(p, 2, 64);
                p += __shfl_xor(p, 4, 64);
                p += __shfl_xor(p, 8, 64);
                if (valid && l15 == 0) preds[orow] = p + fb;
            }
        }
    }

    if (MODE == 0){
        #pragma unroll
        for (int t = 0; t < 8; ++t){
            pbs[t] += __shfl_xor(pbs[t], 16, 64);
            pbs[t] += __shfl_xor(pbs[t], 32, 64);
            pbq[t] += __shfl_xor(pbq[t], 16, 64);
            pbq[t] += __shfl_xor(pbq[t], 32, 64);
        }
        if (lane < 16){
            #pragma unroll
            for (int t = 0; t < 8; ++t){
                atomicAdd(&lsum[t * 16 + lane], pbs[t]);
                atomicAdd(&lsq [t * 16 + lane], pbq[t]);
            }
        }
        __syncthreads();
        if (threadIdx.x < 128){
            atomicAdd(&bnsum[threadIdx.x],   lsum[threadIdx.x]);
            atomicAdd(&bnsumsq[threadIdx.x], lsq[threadIdx.x]);
        }
    }
}

// ---------- BN finalize + effective layer-2 bias (b2 + shift @ W2r) ----------
__global__ void k_bnfinal(const float* __restrict__ bnsum, const float* __restrict__ bnsumsq,
                          const float* __restrict__ gamma, const float* __restrict__ beta,
                          const float* __restrict__ W2r, const float* __restrict__ b2,
                          float* __restrict__ scale, float* __restrict__ shift,
                          float* __restrict__ bias2, int N){
    __shared__ float sh_l[128];
    int t = threadIdx.x;
    float invN = 1.0f / (float)N;
    float mu  = bnsum[t] * invN;
    float var = fmaxf(bnsumsq[t] * invN - mu * mu, 0.f);
    float istd = 1.0f / sqrtf(var + 1e-5f);
    float sc = gamma[t] * istd;
    float sf = beta[t] - mu * sc;
    scale[t] = sc; shift[t] = sf; sh_l[t] = sf;
    __syncthreads();
    float acc = b2[t];
    for (int k = 0; k < 128; ++k) acc += sh_l[k] * W2r[k * 128 + t];
    bias2[t] = acc;
}

__global__ void k_sent(float* __restrict__ preds, int N, float val){
    int i = blockIdx.x * 256 + threadIdx.x;
    if (i < N) preds[i] = val;
}

// ---------- launch ----------
extern "C" void kernel_launch(void* const* d_in, const int* in_sizes, int n_in,
                              void* d_out, int out_size, void* d_ws, size_t ws_size,
                              hipStream_t stream){
    const int N = in_sizes[0] / 128;
    const int E = in_sizes[1] / 2;

    const float* x    = (const float*)d_in[0];
    const int*   ei   = (const int*)d_in[1];
    const int*   src  = ei;
    const int*   dst  = ei + E;
    const float* W1l  = (const float*)d_in[2];
    const float* b1   = (const float*)d_in[3];
    const float* W1r  = (const float*)d_in[4];
    const float* gam  = (const float*)d_in[5];
    const float* bet  = (const float*)d_in[6];
    const float* W2l  = (const float*)d_in[7];
    const float* b2   = (const float*)d_in[8];
    const float* W2r  = (const float*)d_in[9];
    const float* fcW  = (const float*)d_in[10];
    const float* fcb  = (const float*)d_in[11];

    float* preds = (float*)d_out;                 // f32 [N]
    float* Emb   = preds + N;                     // f32 [N,128]
    uint32_t* EmbU = (uint32_t*)Emb;              // Xbf (1st half) + Mb (2nd half) scratch

    char* w = (char*)d_ws;
    auto carve = [&](size_t bytes){ char* p = w; w += (bytes + 255) & ~(size_t)255; return p; };
    int*   counts  = (int*)  carve((size_t)N * 4);
    int*   offs    = (int*)  carve((size_t)N * 4);
    int*   cursor  = (int*)  carve((size_t)N * 4);
    int*   bsums   = (int*)  carve(256 * 4);
    float* bnsum   = (float*)carve(128 * 4);      // contiguous with bnsumsq (one memset)
    float* bnsumsq = (float*)carve(128 * 4);
    float* bnscale = (float*)carve(128 * 4);
    float* bnshift = (float*)carve(128 * 4);
    float* bias2   = (float*)carve(128 * 4);
    int*   ssrc    = (int*)  carve((size_t)E * 4);
    uint32_t* HbfXlo = (uint32_t*)carve((size_t)N * 256);  // Xlo then Hbf (overlay, alias-safe)
    uint16_t* Wpk1 = (uint16_t*)carve(131072);    // packed [kt][hi/lo][128][32]
    uint16_t* Wpk2 = (uint16_t*)carve(131072);
    size_t need = (size_t)(w - (char*)d_ws);
    if (ws_size < need){
        float val = 1024.f + 4.f * (float)((ws_size >> 20) > 255 ? 255 : (ws_size >> 20));
        k_sent<<<(N + 255) / 256, 256, 0, stream>>>(preds, N, val);
        return;
    }

    hipMemsetAsync(counts, 0, (size_t)N * 4, stream);
    hipMemsetAsync(cursor, 0, (size_t)N * 4, stream);
    hipMemsetAsync(bnsum,  0, 1024, stream);

    const int eb = (E + 255) / 256;
    const int NB = (N + 2047) / 2048;
    const int ab = (N + 3) / 4;
    const int gb = (N + 127) / 128;
    const int xb = (N * 64 + 255) / 256;

    k_deg  <<<eb, 256, 0, stream>>>(dst, counts, E);
    k_scan1<<<NB, 256, 0, stream>>>(counts, bsums, N);
    k_scan2<<<1,    1, 0, stream>>>(bsums, NB);
    k_scan3<<<NB, 256, 0, stream>>>(counts, bsums, offs, N);
    k_fill <<<eb, 256, 0, stream>>>(src, dst, offs, cursor, ssrc, E);

    k_x2bf <<<xb, 256, 0, stream>>>(x, EmbU, HbfXlo, N);
    k_wprep<<<128, 256, 0, stream>>>(W1l, W1r, nullptr, Wpk1);

    // layer 1
    k_agg<0> <<<ab, 256, 0, stream>>>(EmbU, 128, offs, counts, ssrc,
                                      nullptr, nullptr, EmbU, N);
    k_gemm<0><<<gb, 256, 0, stream>>>(EmbU, HbfXlo, EmbU, (const uint32_t*)Wpk1, b1,
                                      HbfXlo, nullptr, bnsum, bnsumsq,
                                      nullptr, nullptr, nullptr, N);
    k_bnfinal<<<1, 128, 0, stream>>>(bnsum, bnsumsq, gam, bet, W2r, b2,
                                     bnscale, bnshift, bias2, N);
    k_wprep<<<128, 256, 0, stream>>>(W2l, W2r, bnscale, Wpk2);

    // layer 2
    k_agg<1> <<<ab, 256, 0, stream>>>(HbfXlo, 64, offs, counts, ssrc,
                                      bnscale, bnshift, EmbU, N);
    k_gemm<1><<<gb, 256, 0, stream>>>(HbfXlo, nullptr, EmbU, (const uint32_t*)Wpk2, bias2,
                                      nullptr, Emb, nullptr, nullptr,
                                      fcW, fcb, preds, N);
}

// Round 3
// 376.478 us; speedup vs baseline: 3.5991x; 1.0116x over previous
//
#include <hip/hip_runtime.h>
#include <hip/hip_bf16.h>
#include <stdint.h>

typedef __attribute__((ext_vector_type(8))) __bf16 bf16x8;
typedef __attribute__((ext_vector_type(4))) float  f32x4;

// ---------- bf16 helpers (bf16 pairs packed in uint32, little-endian) ----------
__device__ __forceinline__ float bflo(uint32_t p){ return __uint_as_float(p << 16); }
__device__ __forceinline__ float bfhi(uint32_t p){ return __uint_as_float(p & 0xffff0000u); }
__device__ __forceinline__ uint16_t f2bf(float f){
    uint32_t u = __float_as_uint(f);
    uint32_t r = (u + 0x7fffu + ((u >> 16) & 1u)) >> 16;   // RNE
    return (uint16_t)r;
}
__device__ __forceinline__ uint32_t packbf(float a, float b){
    return (uint32_t)f2bf(a) | ((uint32_t)f2bf(b) << 16);
}
__device__ __forceinline__ f32x4 MFMA(bf16x8 a, bf16x8 b, f32x4 c){
    return __builtin_amdgcn_mfma_f32_16x16x32_bf16(a, b, c, 0, 0, 0);
}

// Mean buffer lives in the SECOND HALF of each f32 Emb row (u32 units):
//   Mb(row) = Emb u32 [row*128 + 64, row*128 + 128).
// Xbf (layer-1 bf16 input) lives in the FIRST HALF: Emb u32 [row*128, row*128+64).
#define MB_IDX(row, lane) ((size_t)(row) * 128 + 64 + (lane))

// ---------- CSR build ----------
__global__ void k_deg(const int* __restrict__ dst, int* __restrict__ counts, int E){
    int e = blockIdx.x * 256 + threadIdx.x;
    if (e < E) atomicAdd(&counts[dst[e]], 1);
}

__global__ void k_scan1(const int* __restrict__ counts, int* __restrict__ bsums, int N){
    __shared__ int lds[256];
    int t = threadIdx.x;
    int base = blockIdx.x * 2048 + t * 8;
    int s = 0;
    #pragma unroll
    for (int i = 0; i < 8; ++i){ int idx = base + i; s += (idx < N) ? counts[idx] : 0; }
    lds[t] = s; __syncthreads();
    for (int off = 128; off > 0; off >>= 1){
        if (t < off) lds[t] += lds[t + off];
        __syncthreads();
    }
    if (t == 0) bsums[blockIdx.x] = lds[0];
}

__global__ void k_scan2(int* bsums, int NB){
    int run = 0;
    for (int i = 0; i < NB; ++i){ int v = bsums[i]; bsums[i] = run; run += v; }
}

__global__ void k_scan3(const int* __restrict__ counts, const int* __restrict__ bsums,
                        int* __restrict__ offs, int N){
    __shared__ int lds[256];
    int t = threadIdx.x;
    int base = blockIdx.x * 2048 + t * 8;
    int local[8];
    int s = 0;
    #pragma unroll
    for (int i = 0; i < 8; ++i){
        int idx = base + i;
        int v = (idx < N) ? counts[idx] : 0;
        local[i] = v; s += v;
    }
    lds[t] = s; __syncthreads();
    for (int off = 1; off < 256; off <<= 1){
        int v = (t >= off) ? lds[t - off] : 0;
        __syncthreads();
        lds[t] += v;
        __syncthreads();
    }
    int run = bsums[blockIdx.x] + (lds[t] - s);
    #pragma unroll
    for (int i = 0; i < 8; ++i){
        int idx = base + i;
        if (idx < N){ offs[idx] = run; run += local[i]; }
    }
}

__global__ void k_fill(const int* __restrict__ src, const int* __restrict__ dst,
                       const int* __restrict__ offs, int* __restrict__ cursor,
                       int* __restrict__ ssrc, int E){
    int e = blockIdx.x * 256 + threadIdx.x;
    if (e < E){
        int d = dst[e];
        int p = atomicAdd(&cursor[d], 1);
        ssrc[offs[d] + p] = src[e];
    }
}

// ---------- x -> bf16 hi (into Emb first half) + bf16 lo residual ----------
__global__ __launch_bounds__(256) void k_x2bf(const float* __restrict__ X,
        uint32_t* __restrict__ XbfE, uint32_t* __restrict__ Xlo, int N){
    int i = blockIdx.x * 256 + threadIdx.x;          // pair index, total N*64
    if (i >= N * 64) return;
    int row = i >> 6, lane = i & 63;
    float2 v = *(const float2*)(X + (size_t)i * 2);
    uint16_t h0 = f2bf(v.x), h1 = f2bf(v.y);
    float r0 = v.x - __uint_as_float((uint32_t)h0 << 16);
    float r1 = v.y - __uint_as_float((uint32_t)h1 << 16);
    XbfE[(size_t)row * 128 + lane] = (uint32_t)h0 | ((uint32_t)h1 << 16);
    Xlo[(size_t)i] = packbf(r0, r1);
}

// ---------- weight prep: packed + bank-swizzled layout for LDS staging ----------
// Wpk u16 layout: [kt(8)][sel(2: hi,lo)][slot(512)][e(8)]
//   slot(c,g) = 4*c + (g ^ ((c>>1)&3))   (bank swizzle: octet of lanes -> 8 distinct
//   16B slots -> all 32 banks once per octet on ds_read_b128)
// source: k<128 -> Wl[k][c], k>=128 -> scale*Wr[k-128][c];  k = kt*32 + g*8 + e
__global__ void k_wprep(const float* __restrict__ Wl, const float* __restrict__ Wr,
                        const float* __restrict__ scale,
                        uint16_t* __restrict__ Wpk){
    int idx = blockIdx.x * 256 + threadIdx.x;        // [0, 32768) = c*256 + k
    int c = idx >> 8, k = idx & 255;
    float v;
    if (k < 128){
        v = Wl[k * 128 + c];
    } else {
        v = Wr[(k - 128) * 128 + c];
        if (scale) v *= scale[k - 128];
    }
    uint16_t h = f2bf(v);
    float r = v - __uint_as_float((uint32_t)h << 16);
    int kt = k >> 5, kk = k & 31;
    int g = kk >> 3, e = kk & 7;
    int slot = (c << 2) | (g ^ ((c >> 1) & 3));
    size_t base = (size_t)kt * 8192 + (size_t)slot * 8 + e;
    Wpk[base]        = h;
    Wpk[base + 4096] = f2bf(r);
}

// ---------- neighbor mean: one wave per node; bf16 source rows ----------
// MODE 0: raw mean.  MODE 1: mean + BN fold (shift only when cnt>0, matching ref).
template<int MODE>
__global__ __launch_bounds__(256) void k_agg(
        const uint32_t* __restrict__ Src, int sstr,
        const int* __restrict__ offs, const int* __restrict__ counts,
        const int* __restrict__ ssrc,
        const float* __restrict__ bnscale, const float* __restrict__ bnshift,
        uint32_t* __restrict__ MbBase, int N){
    int lane = threadIdx.x & 63;
    int node = blockIdx.x * 4 + (threadIdx.x >> 6);
    if (node >= N) return;
    int cnt = counts[node];
    if (cnt < 0) cnt = 0;
    int off = offs[node];
    float a0 = 0.f, a1 = 0.f;
    int j = 0;
    for (; j + 4 <= cnt; j += 4){                     // 4 independent gathers in flight
        int s0 = ssrc[off + j];
        int s1 = ssrc[off + j + 1];
        int s2 = ssrc[off + j + 2];
        int s3 = ssrc[off + j + 3];
        s0 = (s0 < 0) ? 0 : ((s0 >= N) ? (N - 1) : s0);
        s1 = (s1 < 0) ? 0 : ((s1 >= N) ? (N - 1) : s1);
        s2 = (s2 < 0) ? 0 : ((s2 >= N) ? (N - 1) : s2);
        s3 = (s3 < 0) ? 0 : ((s3 >= N) ? (N - 1) : s3);
        uint32_t p0 = Src[(size_t)s0 * sstr + lane];
        uint32_t p1 = Src[(size_t)s1 * sstr + lane];
        uint32_t p2 = Src[(size_t)s2 * sstr + lane];
        uint32_t p3 = Src[(size_t)s3 * sstr + lane];
        a0 += bflo(p0) + bflo(p1) + bflo(p2) + bflo(p3);
        a1 += bfhi(p0) + bfhi(p1) + bfhi(p2) + bfhi(p3);
    }
    for (; j < cnt; ++j){
        int s = ssrc[off + j];
        s = (s < 0) ? 0 : ((s >= N) ? (N - 1) : s);
        uint32_t p = Src[(size_t)s * sstr + lane];
        a0 += bflo(p); a1 += bfhi(p);
    }
    float inv = 1.0f / fmaxf((float)cnt, 1.0f);
    a0 *= inv; a1 *= inv;
    if (MODE == 1){
        int c0 = lane * 2;
        float sh0 = (cnt > 0) ? bnshift[c0]     : 0.f;   // ref: zero-degree mean == 0
        float sh1 = (cnt > 0) ? bnshift[c0 + 1] : 0.f;
        a0 = a0 * bnscale[c0]     + sh0;
        a1 = a1 * bnscale[c0 + 1] + sh1;
    }
    MbBase[MB_IDX(node, lane)] = packbf(a0, a1);
}

// stage one sel-phase (64 KiB: all 8 kt of hi or lo) of B into sB.
// LDS dest is wave-uniform base (+ lane*16 by HW); global src is per-lane.
__device__ __forceinline__ void stage_sel(const uint32_t* Wpk, uint32_t (*sB)[2048],
                                          int wid, int lane, int sel){
    #pragma unroll
    for (int i = 0; i < 16; ++i){
        int ch = wid * 16 + i;                       // 64 chunks of 1 KiB
        int ktv = ch >> 3, part = ch & 7;
        __builtin_amdgcn_global_load_lds(
            Wpk + ktv * 4096 + sel * 2048 + part * 256 + lane * 4,
            &sB[ktv][part * 256], 16, 0, 0);
    }
}

// ---------- MFMA dual-GEMM (K=256 = [mean|own]) + L2-normalize ----------
// Wave owns 32 rows (2 m-tiles), all 128 cols (8 n-tiles).
// All A fragments hoisted to registers up front (one vmcnt wait at barrier 1).
// B staged per sel-phase (hi then lo) into one 64 KiB LDS buffer; the K-loop body
// is pure ds_read_b128 + MFMA with NO barriers (3 barriers total in main path).
// A frag:  lane holds row (lane&15), k = 32*kt + 8*(lane>>4) + e  (contiguous 16B)
// B frag:  swizzled slot; gx = g ^ ((l15>>1)&3)   (conflict-free ds_read_b128)
// C/D:     col = lane&15, row = 4*(lane>>4) + reg   (m89-verified)
// MODE 0: own=Xbf (+Xlo correction on hi); out=relu(norm(.)); Hbf store + BN sums.
// MODE 1: own=Hbf (BN folded into Wpk/bias); out=norm(.); Emb f32 + preds.
template<int MODE>
__global__ __launch_bounds__(256, 2) void k_gemm(
        const uint32_t* Own,                 // MODE0: Xbf in Emb rows (stride 128); MODE1: Hbf (stride 64)
        const uint32_t* OwnLo,               // MODE0 only: Xlo (stride 64; aliases HbfOut)
        const uint32_t* Mb,                  // bf16 means at Emb rows' 2nd half
        const uint32_t* __restrict__ Wpk,    // packed+swizzled [kt][hi/lo][512 slots][8] u16
        const float* __restrict__ bias,      // [128] effective bias
        uint32_t* HbfOut,                    // MODE0 out (aliases OwnLo; alias-safe per-wave)
        float* Emb,                          // MODE1 out (aliases Mb rows; reads precede writes)
        float* __restrict__ bnsum, float* __restrict__ bnsumsq,             // MODE0
        const float* __restrict__ fcW, const float* __restrict__ fcb,       // MODE1
        float* __restrict__ preds, int N){
    __shared__ uint32_t __align__(16) sB[8][2048];   // exactly 64 KiB; lsum/lsq alias after last read
    const int lane = threadIdx.x & 63;
    const int wid  = threadIdx.x >> 6;
    const int l15  = lane & 15;
    const int g    = lane >> 4;
    const int gx4  = (g ^ ((l15 >> 1) & 3)) * 4;     // swizzled 16B sub-slot (u32 units)
    const int ostr = (MODE == 0) ? 128 : 64;
    const int rowb = blockIdx.x * 128 + wid * 32;    // may be >= N: wave stays for staging

    stage_sel(Wpk, sB, wid, lane, 0);                // issue hi-phase staging

    int ar0 = rowb + l15;      if (ar0 >= N) ar0 = N - 1;   // clamped dup rows: discarded
    int ar1 = rowb + 16 + l15; if (ar1 >= N) ar1 = N - 1;

    const uint32_t* mp0 = Mb  + (size_t)ar0 * 128 + 64 + g * 4;
    const uint32_t* mp1 = Mb  + (size_t)ar1 * 128 + 64 + g * 4;
    const uint32_t* op0 = Own + (size_t)ar0 * ostr + g * 4;
    const uint32_t* op1 = Own + (size_t)ar1 * ostr + g * 4;

    // hoist ALL A fragments into registers (independent loads, overlap staging)
    bf16x8 am0[4], am1[4], ao0[4], ao1[4];
    #pragma unroll
    for (int q = 0; q < 4; ++q){
        am0[q] = *(const bf16x8*)(mp0 + q * 16);
        am1[q] = *(const bf16x8*)(mp1 + q * 16);
        ao0[q] = *(const bf16x8*)(op0 + q * 16);
        ao1[q] = *(const bf16x8*)(op1 + q * 16);
    }
    bf16x8 xl0[4], xl1[4];
    if (MODE == 0){
        #pragma unroll
        for (int q = 0; q < 4; ++q){
            xl0[q] = *(const bf16x8*)(OwnLo + (size_t)ar0 * 64 + g * 4 + q * 16);
            xl1[q] = *(const bf16x8*)(OwnLo + (size_t)ar1 * 64 + g * 4 + q * 16);
        }
    }

    f32x4 acc0[8], acc1[8];
    const f32x4 zero = {0.f, 0.f, 0.f, 0.f};
    #pragma unroll
    for (int t = 0; t < 8; ++t){ acc0[t] = zero; acc1[t] = zero; }

    __syncthreads();                                 // barrier 1: hi staged + A in regs

    // ---- phase 1: hi weights (barrier-free) ----
    #pragma unroll
    for (int kt = 0; kt < 8; ++kt){
        bf16x8 a0 = (kt < 4) ? am0[kt] : ao0[kt - 4];
        bf16x8 a1 = (kt < 4) ? am1[kt] : ao1[kt - 4];
        #pragma unroll
        for (int t = 0; t < 8; ++t){
            bf16x8 bh = *(const bf16x8*)(&sB[kt][(t * 16 + l15) * 16 + gx4]);
            acc0[t] = MFMA(a0, bh, acc0[t]);
            acc1[t] = MFMA(a1, bh, acc1[t]);
            if (MODE == 0 && kt >= 4){               // x_lo correction reuses bh
                acc0[t] = MFMA(xl0[kt - 4], bh, acc0[t]);
                acc1[t] = MFMA(xl1[kt - 4], bh, acc1[t]);
            }
        }
    }

    __syncthreads();                                 // barrier 2: all hi reads done
    stage_sel(Wpk, sB, wid, lane, 1);                // issue lo-phase staging
    __syncthreads();                                 // barrier 3: lo staged

    // ---- phase 2: lo weights (barrier-free) ----
    #pragma unroll
    for (int kt = 0; kt < 8; ++kt){
        bf16x8 a0 = (kt < 4) ? am0[kt] : ao0[kt - 4];
        bf16x8 a1 = (kt < 4) ? am1[kt] : ao1[kt - 4];
        #pragma unroll
        for (int t = 0; t < 8; ++t){
            bf16x8 bl = *(const bf16x8*)(&sB[kt][(t * 16 + l15) * 16 + gx4]);
            acc0[t] = MFMA(a0, bl, acc0[t]);
            acc1[t] = MFMA(a1, bl, acc1[t]);
        }
    }

    // ---- epilogue ----
    float bv[8];
    #pragma unroll
    for (int t = 0; t < 8; ++t) bv[t] = bias[t * 16 + l15];

    float fw[4]; float fb = 0.f;
    if (MODE == 1){
        #pragma unroll
        for (int t = 0; t < 4; ++t) fw[t] = fcW[t * 16 + l15];
        fb = fcb[0];
    }

    float pbs[8], pbq[8];
    #pragma unroll
    for (int t = 0; t < 8; ++t){ pbs[t] = 0.f; pbq[t] = 0.f; }

    #pragma unroll
    for (int m = 0; m < 2; ++m){
        #pragma unroll
        for (int j = 0; j < 4; ++j){
            int orow = rowb + m * 16 + 4 * g + j;
            bool valid = orow < N;
            float o[8]; float ss = 0.f;
            #pragma unroll
            for (int t = 0; t < 8; ++t){
                o[t] = (m == 0 ? acc0[t][j] : acc1[t][j]) + bv[t];
                ss += o[t] * o[t];
            }
            ss += __shfl_xor(ss, 1, 64);
            ss += __shfl_xor(ss, 2, 64);
            ss += __shfl_xor(ss, 4, 64);
            ss += __shfl_xor(ss, 8, 64);
            float inv = 1.0f / fmaxf(sqrtf(ss), 1e-12f);
            if (MODE == 0){
                #pragma unroll
                for (int t = 0; t < 8; ++t){
                    float v = fmaxf(o[t] * inv, 0.f);
                    float pv = __shfl_xor(v, 1, 64);          // partner col (uniform exec)
                    if (valid){
                        pbs[t] += v; pbq[t] += v * v;
                        if (!(lane & 1))
                            HbfOut[(size_t)orow * 64 + t * 8 + (l15 >> 1)] = packbf(v, pv);
                    }
                }
            } else {
                float p = 0.f;
                #pragma unroll
                for (int t = 0; t < 8; ++t){
                    float v = o[t] * inv;
                    if (valid) Emb[(size_t)orow * 128 + t * 16 + l15] = v;
                    if (t < 4) p += v * fw[t];
                }
                p += __shfl_xor(p, 1, 64);
                p += __shfl_xor(p, 2, 64);
                p += __shfl_xor(p, 4, 64);
                p += __shfl_xor(p, 8, 64);
                if (valid && l15 == 0) preds[orow] = p + fb;
            }
        }
    }

    if (MODE == 0){
        float* lsum = (float*)&sB[0][0];             // sB dead after phase 2: reuse as reduce buf
        float* lsq  = lsum + 128;
        #pragma unroll
        for (int t = 0; t < 8; ++t){
            pbs[t] += __shfl_xor(pbs[t], 16, 64);
            pbs[t] += __shfl_xor(pbs[t], 32, 64);
            pbq[t] += __shfl_xor(pbq[t], 16, 64);
            pbq[t] += __shfl_xor(pbq[t], 32, 64);
        }
        __syncthreads();                             // all waves done reading sB
        if (threadIdx.x < 128){ lsum[threadIdx.x] = 0.f; lsq[threadIdx.x] = 0.f; }
        __syncthreads();
        if (lane < 16){
            #pragma unroll
            for (int t = 0; t < 8; ++t){
                atomicAdd(&lsum[t * 16 + lane], pbs[t]);
                atomicAdd(&lsq [t * 16 + lane], pbq[t]);
            }
        }
        __syncthreads();
        if (threadIdx.x < 128){
            atomicAdd(&bnsum[threadIdx.x],   lsum[threadIdx.x]);
            atomicAdd(&bnsumsq[threadIdx.x], lsq[threadIdx.x]);
        }
    }
}

// ---------- BN finalize + effective layer-2 bias (b2 + shift @ W2r) ----------
__global__ void k_bnfinal(const float* __restrict__ bnsum, const float* __restrict__ bnsumsq,
                          const float* __restrict__ gamma, const float* __restrict__ beta,
                          const float* __restrict__ W2r, const float* __restrict__ b2,
                          float* __restrict__ scale, float* __restrict__ shift,
                          float* __restrict__ bias2, int N){
    __shared__ float sh_l[128];
    int t = threadIdx.x;
    float invN = 1.0f / (float)N;
    float mu  = bnsum[t] * invN;
    float var = fmaxf(bnsumsq[t] * invN - mu * mu, 0.f);
    float istd = 1.0f / sqrtf(var + 1e-5f);
    float sc = gamma[t] * istd;
    float sf = beta[t] - mu * sc;
    scale[t] = sc; shift[t] = sf; sh_l[t] = sf;
    __syncthreads();
    float acc = b2[t];
    for (int k = 0; k < 128; ++k) acc += sh_l[k] * W2r[k * 128 + t];
    bias2[t] = acc;
}

__global__ void k_sent(float* __restrict__ preds, int N, float val){
    int i = blockIdx.x * 256 + threadIdx.x;
    if (i < N) preds[i] = val;
}

// ---------- launch ----------
extern "C" void kernel_launch(void* const* d_in, const int* in_sizes, int n_in,
                              void* d_out, int out_size, void* d_ws, size_t ws_size,
                              hipStream_t stream){
    const int N = in_sizes[0] / 128;
    const int E = in_sizes[1] / 2;

    const float* x    = (const float*)d_in[0];
    const int*   ei   = (const int*)d_in[1];
    const int*   src  = ei;
    const int*   dst  = ei + E;
    const float* W1l  = (const float*)d_in[2];
    const float* b1   = (const float*)d_in[3];
    const float* W1r  = (const float*)d_in[4];
    const float* gam  = (const float*)d_in[5];
    const float* bet  = (const float*)d_in[6];
    const float* W2l  = (const float*)d_in[7];
    const float* b2   = (const float*)d_in[8];
    const float* W2r  = (const float*)d_in[9];
    const float* fcW  = (const float*)d_in[10];
    const float* fcb  = (const float*)d_in[11];

    float* preds = (float*)d_out;                 // f32 [N]
    float* Emb   = preds + N;                     // f32 [N,128]
    uint32_t* EmbU = (uint32_t*)Emb;              // Xbf (1st half) + Mb (2nd half) scratch

    char* w = (char*)d_ws;
    auto carve = [&](size_t bytes){ char* p = w; w += (bytes + 255) & ~(size_t)255; return p; };
    int*   counts  = (int*)  carve((size_t)N * 4);
    int*   offs    = (int*)  carve((size_t)N * 4);
    int*   cursor  = (int*)  carve((size_t)N * 4);
    int*   bsums   = (int*)  carve(256 * 4);
    float* bnsum   = (float*)carve(128 * 4);      // contiguous with bnsumsq (one memset)
    float* bnsumsq = (float*)carve(128 * 4);
    float* bnscale = (float*)carve(128 * 4);
    float* bnshift = (float*)carve(128 * 4);
    float* bias2   = (float*)carve(128 * 4);
    int*   ssrc    = (int*)  carve((size_t)E * 4);
    uint32_t* HbfXlo = (uint32_t*)carve((size_t)N * 256);  // Xlo then Hbf (overlay, alias-safe)
    uint16_t* Wpk1 = (uint16_t*)carve(131072);    // packed+swizzled [kt][hi/lo][512][8]
    uint16_t* Wpk2 = (uint16_t*)carve(131072);
    size_t need = (size_t)(w - (char*)d_ws);
    if (ws_size < need){
        float val = 1024.f + 4.f * (float)((ws_size >> 20) > 255 ? 255 : (ws_size >> 20));
        k_sent<<<(N + 255) / 256, 256, 0, stream>>>(preds, N, val);
        return;
    }

    hipMemsetAsync(counts, 0, (size_t)N * 4, stream);
    hipMemsetAsync(cursor, 0, (size_t)N * 4, stream);
    hipMemsetAsync(bnsum,  0, 1024, stream);

    const int eb = (E + 255) / 256;
    const int NB = (N + 2047) / 2048;
    const int ab = (N + 3) / 4;
    const int gb = (N + 127) / 128;
    const int xb = (N * 64 + 255) / 256;

    k_deg  <<<eb, 256, 0, stream>>>(dst, counts, E);
    k_scan1<<<NB, 256, 0, stream>>>(counts, bsums, N);
    k_scan2<<<1,    1, 0, stream>>>(bsums, NB);
    k_scan3<<<NB, 256, 0, stream>>>(counts, bsums, offs, N);
    k_fill <<<eb, 256, 0, stream>>>(src, dst, offs, cursor, ssrc, E);

    k_x2bf <<<xb, 256, 0, stream>>>(x, EmbU, HbfXlo, N);
    k_wprep<<<128, 256, 0, stream>>>(W1l, W1r, nullptr, Wpk1);

    // layer 1
    k_agg<0> <<<ab, 256, 0, stream>>>(EmbU, 128, offs, counts, ssrc,
                                      nullptr, nullptr, EmbU, N);
    k_gemm<0><<<gb, 256, 0, stream>>>(EmbU, HbfXlo, EmbU, (const uint32_t*)Wpk1, b1,
                                      HbfXlo, nullptr, bnsum, bnsumsq,
                                      nullptr, nullptr, nullptr, N);
    k_bnfinal<<<1, 128, 0, stream>>>(bnsum, bnsumsq, gam, bet, W2r, b2,
                                     bnscale, bnshift, bias2, N);
    k_wprep<<<128, 256, 0, stream>>>(W2l, W2r, bnscale, Wpk2);

    // layer 2
    k_agg<1> <<<ab, 256, 0, stream>>>(HbfXlo, 64, offs, counts, ssrc,
                                      bnscale, bnshift, EmbU, N);
    k_gemm<1><<<gb, 256, 0, stream>>>(HbfXlo, nullptr, EmbU, (const uint32_t*)Wpk2, bias2,
                                      nullptr, Emb, nullptr, nullptr,
                                      fcW, fcb, preds, N);
}